// Round 7
// baseline (498.722 us; speedup 1.0000x reference)
//
#include <hip/hip_runtime.h>
#include <math.h>

// Problem constants
#define TT 2048        // b*n tokens
#define DD 1024        // model dim
#define HH 8           // heads
#define NKK 256        // keys per half
#define KDD 128        // key dim
#define TK 8           // top-k
#define NEE 65536      // experts

#define DELTA 1e-4f    // top-k ambiguity threshold (worst-case fused split-bf16 err ~7e-5)

// ws layout (bytes) — total EXACTLY 60817408 B (58 MiB), the proven-safe footprint.
// W2h/W2l occupy the old Q slot (16 MiB). SIM is now [2048][4096] fp32 (32 MiB).
#define WS_PS    0           // double[32][1024]                  (256 KiB)
#define WS_PQ    262144      // double[32][1024]                  (256 KiB)
#define WS_A     524288      // float[1024] scale                 (4 KiB)
#define WS_B2    528384      // float[1024] shift                 (4 KiB)
#define WS_FLAG  532480      // int[16384]                        (64 KiB)
#define WS_XNH   1048576     // ushort[2048][1024] bf16 hi        (4 MiB)
#define WS_XNL   5242880     // ushort[2048][1024] bf16 lo        (4 MiB)
#define WS_W2H   9437184     // ushort[4096][1024] bf16 hi        (8 MiB)
#define WS_W2L   17825792    // ushort[4096][1024] bf16 lo        (8 MiB)
#define WS_SIM   26214400    // float[2048][4096]                 (32 MiB)
#define WS_IDX   59768832    // int[2048][8][8]                   (512 KiB)
#define WS_SMW   60293120    // float[2048][8][8]                 (512 KiB)
// end = 60817408

typedef short bf16x8 __attribute__((ext_vector_type(8)));
typedef float f32x4 __attribute__((ext_vector_type(4)));

// ---------------- BatchNorm statistics ----------------
__global__ __launch_bounds__(256) void bn_partial(const float* __restrict__ x,
    double* __restrict__ ps, double* __restrict__ pq)
{
    int col = blockIdx.x * 256 + threadIdx.x;
    int r0 = blockIdx.y * 64;
    double s = 0.0, q = 0.0;
    for (int r = 0; r < 64; ++r) {
        double v = (double)x[(size_t)(r0 + r) * DD + col];
        s += v; q += v * v;
    }
    ps[(size_t)blockIdx.y * DD + col] = s;
    pq[(size_t)blockIdx.y * DD + col] = q;
}

__global__ __launch_bounds__(256) void bn_final(const double* __restrict__ ps,
    const double* __restrict__ pq, const float* __restrict__ gamma,
    const float* __restrict__ beta, float* __restrict__ Aout, float* __restrict__ Bout)
{
    int col = blockIdx.x * 256 + threadIdx.x;
    double s = 0.0, q = 0.0;
    for (int g = 0; g < 32; ++g) { s += ps[(size_t)g * DD + col]; q += pq[(size_t)g * DD + col]; }
    double mu = s / 2048.0;
    double var = q / 2048.0 - mu * mu;
    double rstd = 1.0 / sqrt(var + 1e-5);
    Aout[col] = (float)((double)gamma[col] * rstd);
    Bout[col] = (float)((double)beta[col] - mu * (double)gamma[col] * rstd);
}

// fp32 -> bf16 hi/lo split
__device__ __forceinline__ void split_bf16(float v, unsigned short& h, unsigned short& l)
{
    __bf16 hb = (__bf16)v;
    float hf = (float)hb;
    __bf16 lb = (__bf16)(v - hf);
    h = __builtin_bit_cast(unsigned short, hb);
    l = __builtin_bit_cast(unsigned short, lb);
}

__global__ __launch_bounds__(256) void xn_kernel(const float* __restrict__ x,
    const float* __restrict__ A, const float* __restrict__ B2,
    unsigned short* __restrict__ XNh, unsigned short* __restrict__ XNl)
{
    int i = blockIdx.x * 256 + threadIdx.x;
    float4 v = ((const float4*)x)[i];
    int c = (i & 255) << 2;
    v.x = v.x * A[c + 0] + B2[c + 0];
    v.y = v.y * A[c + 1] + B2[c + 1];
    v.z = v.z * A[c + 2] + B2[c + 2];
    v.w = v.w * A[c + 3] + B2[c + 3];
    ushort4 h, l;
    split_bf16(v.x, h.x, l.x); split_bf16(v.y, h.y, l.y);
    split_bf16(v.z, h.z, l.z); split_bf16(v.w, h.w, l.w);
    ((ushort4*)XNh)[i] = h;
    ((ushort4*)XNl)[i] = l;
}

// ---------------- W2 = keys @ w_q  (fp32 accum -> bf16 hi/lo) ----------------
// W2[n = p*2048 + h*256 + key][d] = sum_kd keys[h][key][p][kd] * w_q[p*1024+h*128+kd][d]
// grid 512 = p(2) * h(8) * kb(32); block 256; each block: 8 keys, all 1024 d.
__global__ __launch_bounds__(256) void w2_kernel(
    const float* __restrict__ keys, const float* __restrict__ wq,
    unsigned short* __restrict__ W2h, unsigned short* __restrict__ W2l)
{
    int bid = blockIdx.x;
    int p = bid >> 8, h = (bid >> 5) & 7, kb = bid & 31;
    int tid = threadIdx.x;
    __shared__ float ks_[8][128];
    {
        int key = tid >> 5, kd0 = (tid & 31) << 2;
        float4 kv = *(const float4*)(keys +
            (((size_t)(h * NKK + kb * 8 + key) * 2 + p) * KDD) + kd0);
        *(float4*)&ks_[key][kd0] = kv;
    }
    __syncthreads();
    float acc[8][4] = {};
    int c0 = tid << 2;
    const float* wbase = wq + ((size_t)(p * 8 + h) * KDD) * DD + c0;
    for (int kd = 0; kd < KDD; ++kd) {
        float4 wv = *(const float4*)(wbase + (size_t)kd * DD);
#pragma unroll
        for (int key = 0; key < 8; ++key) {
            float kvv = ks_[key][kd];
            acc[key][0] += kvv * wv.x; acc[key][1] += kvv * wv.y;
            acc[key][2] += kvv * wv.z; acc[key][3] += kvv * wv.w;
        }
    }
#pragma unroll
    for (int key = 0; key < 8; ++key) {
        size_t n = (size_t)p * 2048 + h * NKK + kb * 8 + key;
        ushort4 hh, ll;
        split_bf16(acc[key][0], hh.x, ll.x); split_bf16(acc[key][1], hh.y, ll.y);
        split_bf16(acc[key][2], hh.z, ll.z); split_bf16(acc[key][3], hh.w, ll.w);
        *(ushort4*)(W2h + n * DD + c0) = hh;
        *(ushort4*)(W2l + n * DD + c0) = ll;
    }
}

// ---------------- fused sim GEMM: SIM = XN @ W2.T  (split-bf16 MFMA) ----------------
// M=2048, N=4096, K=1024. C = Ah*Bh + Ah*Bl + Al*Bh (fp32 accum).
// 128x128 tile, BK=64, 4 waves 2x2 (64x64/wave), grid 16x32 = 512 blocks (2/CU).
// LDS [128][64] per digit tile; XOR swizzle: 16B slot' = slot ^ (row & 7),
// applied identically on ds_write and ds_read (same involution both sides).
__global__ __launch_bounds__(256) void gemm_sim(
    const unsigned short* __restrict__ Ah, const unsigned short* __restrict__ Al,
    const unsigned short* __restrict__ Bh, const unsigned short* __restrict__ Bl,
    float* __restrict__ C)
{
    __shared__ unsigned short sAh[128][64], sAl[128][64];
    __shared__ unsigned short sBh[128][64], sBl[128][64];
    int tid = threadIdx.x, lane = tid & 63, w = tid >> 6;
    int wm = w >> 1, wn = w & 1;
    int m0 = blockIdx.x * 128, n0 = blockIdx.y * 128;

    f32x4 acc[4][4];
#pragma unroll
    for (int i = 0; i < 4; ++i)
#pragma unroll
        for (int j = 0; j < 4; ++j)
#pragma unroll
            for (int r = 0; r < 4; ++r) acc[i][j][r] = 0.f;

    int srow = tid >> 1, shalf = tid & 1;          // row 0..127, k-half 0..1
    const size_t gAoff = (size_t)(m0 + srow) * 1024 + (shalf << 5);
    const size_t gBoff = (size_t)(n0 + srow) * 1024 + (shalf << 5);

    for (int k0 = 0; k0 < 1024; k0 += 64) {
#pragma unroll
        for (int c = 0; c < 4; ++c) {
            int sp = ((shalf << 2) + c) ^ (srow & 7);   // swizzled 16B slot
            float4 vah = *(const float4*)(Ah + gAoff + k0 + (c << 3));
            float4 val = *(const float4*)(Al + gAoff + k0 + (c << 3));
            float4 vbh = *(const float4*)(Bh + gBoff + k0 + (c << 3));
            float4 vbl = *(const float4*)(Bl + gBoff + k0 + (c << 3));
            *(float4*)&sAh[srow][sp << 3] = vah;
            *(float4*)&sAl[srow][sp << 3] = val;
            *(float4*)&sBh[srow][sp << 3] = vbh;
            *(float4*)&sBl[srow][sp << 3] = vbl;
        }
        __syncthreads();
#pragma unroll
        for (int ks = 0; ks < 2; ++ks) {
            bf16x8 fah[4], fal[4], fbh[4], fbl[4];
#pragma unroll
            for (int i = 0; i < 4; ++i) {
                int ra = wm * 64 + i * 16 + (lane & 15);
                int sa = ((ks << 2) + (lane >> 4)) ^ (ra & 7);
                fah[i] = *(const bf16x8*)&sAh[ra][sa << 3];
                fal[i] = *(const bf16x8*)&sAl[ra][sa << 3];
                int rb = wn * 64 + i * 16 + (lane & 15);
                int sb = ((ks << 2) + (lane >> 4)) ^ (rb & 7);
                fbh[i] = *(const bf16x8*)&sBh[rb][sb << 3];
                fbl[i] = *(const bf16x8*)&sBl[rb][sb << 3];
            }
#pragma unroll
            for (int i = 0; i < 4; ++i)
#pragma unroll
                for (int j = 0; j < 4; ++j) {
                    acc[i][j] = __builtin_amdgcn_mfma_f32_16x16x32_bf16(fah[i], fbh[j], acc[i][j], 0, 0, 0);
                    acc[i][j] = __builtin_amdgcn_mfma_f32_16x16x32_bf16(fah[i], fbl[j], acc[i][j], 0, 0, 0);
                    acc[i][j] = __builtin_amdgcn_mfma_f32_16x16x32_bf16(fal[i], fbh[j], acc[i][j], 0, 0, 0);
                }
        }
        __syncthreads();
    }

    // epilogue: C/D layout col=lane&15, row=(lane>>4)*4+r (verified r6)
    int crow = m0 + wm * 64 + ((lane >> 4) << 2);
    int ccol = n0 + wn * 64 + (lane & 15);
#pragma unroll
    for (int i = 0; i < 4; ++i)
#pragma unroll
        for (int j = 0; j < 4; ++j)
#pragma unroll
            for (int r = 0; r < 4; ++r)
                C[(size_t)(crow + i * 16 + r) * 4096 + ccol + j * 16] = acc[i][j][r];
}

// ---------------- shared top-k core pieces ----------------
__device__ __forceinline__ void stage1_half(float v0, float v1, float v2, float v3,
    int lane, int mode, float& keep_v, int& keep_i, float& g7, float& g8)
{
#pragma unroll
    for (int it = 0; it < 9; ++it) {
        float bv = v0; int bj = 0;
        if (v1 > bv) { bv = v1; bj = 1; }
        if (v2 > bv) { bv = v2; bj = 2; }
        if (v3 > bv) { bv = v3; bj = 3; }
        int mi = lane + (bj << 6);
        float mv = bv;
#pragma unroll
        for (int off = 1; off < 64; off <<= 1) {
            float ov = __shfl_xor(mv, off);
            int oi = __shfl_xor(mi, off);
            if (ov > mv || (ov == mv && oi < mi)) { mv = ov; mi = oi; }
        }
        int keeper = (mode == 0) ? (lane >> 3) : (lane & 7);
        if (it < 8 && keeper == it) { keep_v = mv; keep_i = mi; }
        if (it == 7) g7 = mv;
        if (it == 8) g8 = mv;
        if (mi == lane)            v0 = -INFINITY;
        else if (mi == lane + 64)  v1 = -INFINITY;
        else if (mi == lane + 128) v2 = -INFINITY;
        else if (mi == lane + 192) v3 = -INFINITY;
    }
}

__device__ __forceinline__ float stage2_write(float vx, float vy, int vix, int viy,
    int lane, int base, int* __restrict__ IDX, float* __restrict__ SMW)
{
    float mycs = vx + vy;
    int cidx = vix * NKK + viy;
    float s2[9]; int wi2[8];
#pragma unroll
    for (int it = 0; it < 9; ++it) {
        float mv = mycs; int ml = lane;
#pragma unroll
        for (int off = 1; off < 64; off <<= 1) {
            float ov = __shfl_xor(mv, off);
            int ol = __shfl_xor(ml, off);
            if (ov > mv || (ov == mv && ol < ml)) { mv = ov; ml = ol; }
        }
        s2[it] = mv;
        if (it < 8) wi2[it] = __shfl(cidx, ml);
        if (lane == ml) mycs = -INFINITY;
    }
    float e[8]; float esum = 0.f;
#pragma unroll
    for (int it = 0; it < 8; ++it) { e[it] = expf(s2[it] - s2[0]); esum += e[it]; }
    float inv = 1.f / esum;
    if (lane == 0) {
#pragma unroll
        for (int it = 0; it < 8; ++it) { IDX[base + it] = wi2[it]; SMW[base + it] = e[it] * inv; }
    }
    return s2[7] - s2[8];
}

// ---------------- two-stage top-k + softmax + ambiguity flag ----------------
// SIM layout: [t][n=4096], n = p*2048 + h*256 + key
__global__ __launch_bounds__(256) void topk_kernel(
    const float* __restrict__ SIM, int* __restrict__ IDX, float* __restrict__ SMW,
    int* __restrict__ FLAG)
{
    int gw = blockIdx.x * 4 + (threadIdx.x >> 6);   // row = t*8+h
    int lane = threadIdx.x & 63;
    int t = gw >> 3, h = gw & 7;

    float vx = 0.f, vy = 0.f; int vix = 0, viy = 0;
    float g7a, g8a, g7b, g8b;

    const float* s0 = SIM + (size_t)t * 4096 + h * NKK;
    stage1_half(s0[lane], s0[lane + 64], s0[lane + 128], s0[lane + 192],
                lane, 0, vx, vix, g7a, g8a);
    const float* s1 = SIM + (size_t)t * 4096 + 2048 + h * NKK;
    stage1_half(s1[lane], s1[lane + 64], s1[lane + 128], s1[lane + 192],
                lane, 1, vy, viy, g7b, g8b);

    float gap2 = stage2_write(vx, vy, vix, viy, lane, gw * TK, IDX, SMW);
    if (lane == 0) {
        FLAG[gw] = ((g7a - g8a) < DELTA) | ((g7b - g8b) < DELTA) | (gap2 < DELTA);
    }
}

// ---------------- fp32 fixup for ambiguous rows (one wave per row) ----------------
__global__ __launch_bounds__(64) void fixup_kernel(
    const float* __restrict__ x, const float* __restrict__ Aw,
    const float* __restrict__ B2w, const float* __restrict__ w_q,
    const float* __restrict__ keys, const int* __restrict__ FLAG,
    int* __restrict__ IDX, float* __restrict__ SMW)
{
    int row = blockIdx.x;
    if (!FLAG[row]) return;
    int t = row >> 3, h = row & 7;
    int lane = threadIdx.x;
    __shared__ float xs[DD];
    __shared__ float qs[2][KDD];
    __shared__ float sims[2][NKK];

    for (int c = lane * 4; c < DD; c += 256) {
        float4 v = *(const float4*)(x + (size_t)t * DD + c);
        v.x = v.x * Aw[c + 0] + B2w[c + 0];
        v.y = v.y * Aw[c + 1] + B2w[c + 1];
        v.z = v.z * Aw[c + 2] + B2w[c + 2];
        v.w = v.w * Aw[c + 3] + B2w[c + 3];
        *(float4*)&xs[c] = v;
    }
    __syncthreads();

    for (int p = 0; p < 2; ++p)
        for (int j = 0; j < 2; ++j) {
            int kd = lane + j * 64;
            const float* wr = w_q + ((size_t)((p * HH + h) * KDD) + kd) * DD;
            float acc = 0.f;
            for (int d = 0; d < DD; d += 4) {
                float4 wv = *(const float4*)(wr + d);
                acc += xs[d] * wv.x + xs[d + 1] * wv.y + xs[d + 2] * wv.z + xs[d + 3] * wv.w;
            }
            qs[p][kd] = acc;
        }
    __syncthreads();

    for (int p = 0; p < 2; ++p)
        for (int j = 0; j < 4; ++j) {
            int key = lane + j * 64;
            const float* kr = keys + (((size_t)h * NKK + key) * 2 + p) * KDD;
            float acc = 0.f;
            for (int d = 0; d < KDD; d += 4) {
                float4 kv = *(const float4*)(kr + d);
                acc += qs[p][d] * kv.x + qs[p][d + 1] * kv.y + qs[p][d + 2] * kv.z + qs[p][d + 3] * kv.w;
            }
            sims[p][key] = acc;
        }
    __syncthreads();

    float vx = 0.f, vy = 0.f; int vix = 0, viy = 0;
    float d0, d1, d2, d3;
    stage1_half(sims[0][lane], sims[0][lane + 64], sims[0][lane + 128], sims[0][lane + 192],
                lane, 0, vx, vix, d0, d1);
    stage1_half(sims[1][lane], sims[1][lane + 64], sims[1][lane + 128], sims[1][lane + 192],
                lane, 1, vy, viy, d2, d3);
    stage2_write(vx, vy, vix, viy, lane, row * TK, IDX, SMW);
}

// ---------------- expert gather + gelu + weighted combine (round-1 proven) ----------------
__global__ __launch_bounds__(256) void expert_kernel(
    const float* __restrict__ x, const int* __restrict__ IDX,
    const float* __restrict__ SMW, const float* __restrict__ key_in,
    const float* __restrict__ key_out, float* __restrict__ out)
{
    int t = blockIdx.x;
    int tid = threadIdx.x, lane = tid & 63, w = tid >> 6;
    __shared__ float xs[DD];
    __shared__ float part[4][DD];
    *(float4*)&xs[tid * 4] = *(const float4*)(x + (size_t)t * DD + tid * 4);
    __syncthreads();
    float4 xin[4];
#pragma unroll
    for (int r = 0; r < 4; ++r) xin[r] = *(const float4*)&xs[r * 256 + lane * 4];
    float4 acc[4];
#pragma unroll
    for (int r = 0; r < 4; ++r) acc[r] = make_float4(0.f, 0.f, 0.f, 0.f);

    for (int hh2 = 0; hh2 < 2; ++hh2) {
        int hh = w * 2 + hh2;
        for (int k = 0; k < TK; ++k) {
            int base = (t * HH + hh) * TK + k;
            int e = IDX[base];
            float wt = SMW[base];
            const float* ki = key_in + (size_t)e * DD;
            const float* ko = key_out + (size_t)e * DD;
            float4 kin[4], kout[4];
#pragma unroll
            for (int r = 0; r < 4; ++r) kin[r] = *(const float4*)(ki + r * 256 + lane * 4);
#pragma unroll
            for (int r = 0; r < 4; ++r) kout[r] = *(const float4*)(ko + r * 256 + lane * 4);
            float p = 0.f;
#pragma unroll
            for (int r = 0; r < 4; ++r)
                p += xin[r].x * kin[r].x + xin[r].y * kin[r].y
                   + xin[r].z * kin[r].z + xin[r].w * kin[r].w;
#pragma unroll
            for (int off = 1; off < 64; off <<= 1) p += __shfl_xor(p, off);
            float g = 0.5f * p * (1.f + erff(p * 0.70710678118654752440f));
            float go = g * wt;
#pragma unroll
            for (int r = 0; r < 4; ++r) {
                acc[r].x += go * kout[r].x; acc[r].y += go * kout[r].y;
                acc[r].z += go * kout[r].z; acc[r].w += go * kout[r].w;
            }
        }
    }
#pragma unroll
    for (int r = 0; r < 4; ++r) *(float4*)&part[w][r * 256 + lane * 4] = acc[r];
    __syncthreads();
    int c = tid * 4;
    float4 s0 = *(const float4*)&part[0][c];
    float4 s1 = *(const float4*)&part[1][c];
    float4 s2 = *(const float4*)&part[2][c];
    float4 s3 = *(const float4*)&part[3][c];
    float4 o;
    o.x = (s0.x + s1.x) + (s2.x + s3.x);
    o.y = (s0.y + s1.y) + (s2.y + s3.y);
    o.z = (s0.z + s1.z) + (s2.z + s3.z);
    o.w = (s0.w + s1.w) + (s2.w + s3.w);
    *(float4*)(out + (size_t)t * DD + c) = o;
}

extern "C" void kernel_launch(void* const* d_in, const int* in_sizes, int n_in,
                              void* d_out, int out_size, void* d_ws, size_t ws_size,
                              hipStream_t stream)
{
    const float* x       = (const float*)d_in[0];
    const float* gamma   = (const float*)d_in[1];
    const float* beta    = (const float*)d_in[2];
    const float* w_q     = (const float*)d_in[3];
    const float* keys    = (const float*)d_in[4];
    const float* key_in  = (const float*)d_in[5];
    const float* key_out = (const float*)d_in[6];
    float* out = (float*)d_out;
    char* ws = (char*)d_ws;

    double* ps  = (double*)(ws + WS_PS);
    double* pq  = (double*)(ws + WS_PQ);
    float*  Aw  = (float*)(ws + WS_A);
    float*  B2w = (float*)(ws + WS_B2);
    int*    FLAGw = (int*)(ws + WS_FLAG);
    unsigned short* XNh = (unsigned short*)(ws + WS_XNH);
    unsigned short* XNl = (unsigned short*)(ws + WS_XNL);
    unsigned short* W2h = (unsigned short*)(ws + WS_W2H);
    unsigned short* W2l = (unsigned short*)(ws + WS_W2L);
    float*  SIMw= (float*)(ws + WS_SIM);
    int*    IDXw= (int*)(ws + WS_IDX);
    float*  SMWw= (float*)(ws + WS_SMW);

    bn_partial<<<dim3(4, 32), 256, 0, stream>>>(x, ps, pq);
    bn_final<<<4, 256, 0, stream>>>(ps, pq, gamma, beta, Aw, B2w);
    xn_kernel<<<2048, 256, 0, stream>>>(x, Aw, B2w, XNh, XNl);
    w2_kernel<<<512, 256, 0, stream>>>(keys, w_q, W2h, W2l);
    // SIM = XN @ W2.T : M=2048 N=4096 K=1024, split-bf16 MFMA, 512 blocks
    gemm_sim<<<dim3(16, 32), 256, 0, stream>>>(XNh, XNl, W2h, W2l, SIMw);
    topk_kernel<<<4096, 256, 0, stream>>>(SIMw, IDXw, SMWw, FLAGw);
    fixup_kernel<<<16384, 64, 0, stream>>>(x, Aw, B2w, w_q, keys, FLAGw, IDXw, SMWw);
    expert_kernel<<<2048, 256, 0, stream>>>(x, IDXw, SMWw, key_in, key_out, out);
}

// Round 8
// 385.120 us; speedup vs baseline: 1.2950x; 1.2950x over previous
//
#include <hip/hip_runtime.h>
#include <math.h>

// Problem constants
#define TT 2048        // b*n tokens
#define DD 1024        // model dim
#define HH 8           // heads
#define NKK 256        // keys per half
#define KDD 128        // key dim
#define TK 8           // top-k
#define NEE 65536      // experts

// ws layout (bytes) — EXACTLY the round-1 proven 58-MiB footprint.
#define WS_PS    0           // double[32][1024] partial sums
#define WS_PQ    262144      // double[32][1024] partial sumsq
#define WS_A     524288      // float[1024] scale
#define WS_B2    528384      // float[1024] shift
#define WS_XN    1048576     // float[2048][1024]
#define WS_Q     9437184     // float[2048][2048]
#define WS_SIM   26214400    // float[2][2048][8][256]
#define WS_IDX   59768832    // int[2048][8][8]
#define WS_SMW   60293120    // float[2048][8][8]
// end = 60817408

// ---------------- BatchNorm statistics ----------------
__global__ __launch_bounds__(256) void bn_partial(const float* __restrict__ x,
    double* __restrict__ ps, double* __restrict__ pq)
{
    int col = blockIdx.x * 256 + threadIdx.x;
    int r0 = blockIdx.y * 64;
    double s = 0.0, q = 0.0;
    for (int r = 0; r < 64; ++r) {
        double v = (double)x[(size_t)(r0 + r) * DD + col];
        s += v; q += v * v;
    }
    ps[(size_t)blockIdx.y * DD + col] = s;
    pq[(size_t)blockIdx.y * DD + col] = q;
}

__global__ __launch_bounds__(256) void bn_final(const double* __restrict__ ps,
    const double* __restrict__ pq, const float* __restrict__ gamma,
    const float* __restrict__ beta, float* __restrict__ Aout, float* __restrict__ Bout)
{
    int col = blockIdx.x * 256 + threadIdx.x;
    double s = 0.0, q = 0.0;
    for (int g = 0; g < 32; ++g) { s += ps[(size_t)g * DD + col]; q += pq[(size_t)g * DD + col]; }
    double mu = s / 2048.0;
    double var = q / 2048.0 - mu * mu;      // biased var, matches torch/jax BN
    double rstd = 1.0 / sqrt(var + 1e-5);
    Aout[col] = (float)((double)gamma[col] * rstd);
    Bout[col] = (float)((double)beta[col] - mu * (double)gamma[col] * rstd);
}

__global__ __launch_bounds__(256) void xn_kernel(const float* __restrict__ x,
    const float* __restrict__ A, const float* __restrict__ B2, float* __restrict__ XN)
{
    int i = blockIdx.x * 256 + threadIdx.x;   // float4 index
    float4 v = ((const float4*)x)[i];
    int c = (i & 255) << 2;
    v.x = v.x * A[c + 0] + B2[c + 0];
    v.y = v.y * A[c + 1] + B2[c + 1];
    v.z = v.z * A[c + 2] + B2[c + 2];
    v.w = v.w * A[c + 3] + B2[c + 3];
    ((float4*)XN)[i] = v;
}

// ---------------- fp32 tile GEMM: C[m][n] = sum_k A[m][k]*B[n][k] ----------------
// mode 0: Q = XN @ w_q.T          (M=2048, N=2048, K=1024)
// mode 1: per-(p,h) sim GEMM via blockIdx.z  (M=2048, N=256, K=128)
__global__ __launch_bounds__(256) void gemm_nt(
    const float* __restrict__ Abase, const float* __restrict__ Bbase,
    float* __restrict__ Cbase, int lda, int ldb, int ldc, int Kdim, int mode)
{
    const float* A = Abase; const float* B = Bbase; float* C = Cbase;
    if (mode == 1) {
        int z = blockIdx.z;                 // z = p*8+h
        int p = z >> 3, h = z & 7;
        A += (size_t)z * 128;               // column offset into Q
        B += (size_t)h * (NKK * 2 * KDD) + (size_t)p * KDD;
        C += (size_t)p * ((size_t)TT * HH * NKK) + (size_t)h * NKK;
    }
    __shared__ float As[16][132];
    __shared__ float Bs[16][132];
    int tid = threadIdx.x;
    int tx = tid & 15, ty = tid >> 4;
    int m0 = blockIdx.x * 128, n0 = blockIdx.y * 128;
    float acc[8][8];
#pragma unroll
    for (int i = 0; i < 8; ++i)
#pragma unroll
        for (int j = 0; j < 8; ++j) acc[i][j] = 0.f;

    for (int k0 = 0; k0 < Kdim; k0 += 16) {
#pragma unroll
        for (int it = 0; it < 2; ++it) {
            int li = tid + it * 256;        // 0..511
            int row = li >> 2;              // 0..127
            int kc = (li & 3) << 2;         // 0,4,8,12
            float4 va = *(const float4*)(A + (size_t)(m0 + row) * lda + k0 + kc);
            As[kc + 0][row] = va.x; As[kc + 1][row] = va.y;
            As[kc + 2][row] = va.z; As[kc + 3][row] = va.w;
            float4 vb = *(const float4*)(B + (size_t)(n0 + row) * ldb + k0 + kc);
            Bs[kc + 0][row] = vb.x; Bs[kc + 1][row] = vb.y;
            Bs[kc + 2][row] = vb.z; Bs[kc + 3][row] = vb.w;
        }
        __syncthreads();
#pragma unroll
        for (int k = 0; k < 16; ++k) {
            float a[8], b[8];
            *(float4*)&a[0] = *(const float4*)&As[k][ty * 4];
            *(float4*)&a[4] = *(const float4*)&As[k][64 + ty * 4];
            *(float4*)&b[0] = *(const float4*)&Bs[k][tx * 4];
            *(float4*)&b[4] = *(const float4*)&Bs[k][64 + tx * 4];
#pragma unroll
            for (int i = 0; i < 8; ++i)
#pragma unroll
                for (int j = 0; j < 8; ++j) acc[i][j] += a[i] * b[j];
        }
        __syncthreads();
    }
#pragma unroll
    for (int i = 0; i < 8; ++i) {
        int m = m0 + ((i < 4) ? (ty * 4 + i) : (64 + ty * 4 + (i - 4)));
        float4 c0 = make_float4(acc[i][0], acc[i][1], acc[i][2], acc[i][3]);
        float4 c1 = make_float4(acc[i][4], acc[i][5], acc[i][6], acc[i][7]);
        *(float4*)(C + (size_t)m * ldc + n0 + tx * 4) = c0;
        *(float4*)(C + (size_t)m * ldc + n0 + 64 + tx * 4) = c1;
    }
}

// ---------------- two-stage top-k + softmax (one wave per (t,h)) ----------------
__global__ __launch_bounds__(256) void topk_kernel(
    const float* __restrict__ SIM, int* __restrict__ IDX, float* __restrict__ SMW)
{
    int gw = blockIdx.x * 4 + (threadIdx.x >> 6);   // 0..16383
    int lane = threadIdx.x & 63;
    int t = gw >> 3, h = gw & 7;

    float vx = 0.f, vy = 0.f; int vix = 0, viy = 0;

    // stage 1, p = 0 : lane (lane>>3) keeps the (lane>>3)-th ranked (val,idx)
    {
        const float* s = SIM + ((size_t)t * HH + h) * NKK;
        float v0 = s[lane], v1 = s[lane + 64], v2 = s[lane + 128], v3 = s[lane + 192];
#pragma unroll
        for (int it = 0; it < 8; ++it) {
            float bv = v0; int bj = 0;
            if (v1 > bv) { bv = v1; bj = 1; }
            if (v2 > bv) { bv = v2; bj = 2; }
            if (v3 > bv) { bv = v3; bj = 3; }
            int mi = lane + (bj << 6);
            float mv = bv;
#pragma unroll
            for (int off = 1; off < 64; off <<= 1) {
                float ov = __shfl_xor(mv, off);
                int oi = __shfl_xor(mi, off);
                if (ov > mv || (ov == mv && oi < mi)) { mv = ov; mi = oi; }
            }
            if ((lane >> 3) == it) { vx = mv; vix = mi; }
            if (mi == lane)            v0 = -INFINITY;
            else if (mi == lane + 64)  v1 = -INFINITY;
            else if (mi == lane + 128) v2 = -INFINITY;
            else if (mi == lane + 192) v3 = -INFINITY;
        }
    }
    // stage 1, p = 1 : lane (lane&7) keeps the (lane&7)-th ranked (val,idx)
    {
        const float* s = SIM + (size_t)TT * HH * NKK + ((size_t)t * HH + h) * NKK;
        float v0 = s[lane], v1 = s[lane + 64], v2 = s[lane + 128], v3 = s[lane + 192];
#pragma unroll
        for (int it = 0; it < 8; ++it) {
            float bv = v0; int bj = 0;
            if (v1 > bv) { bv = v1; bj = 1; }
            if (v2 > bv) { bv = v2; bj = 2; }
            if (v3 > bv) { bv = v3; bj = 3; }
            int mi = lane + (bj << 6);
            float mv = bv;
#pragma unroll
            for (int off = 1; off < 64; off <<= 1) {
                float ov = __shfl_xor(mv, off);
                int oi = __shfl_xor(mi, off);
                if (ov > mv || (ov == mv && oi < mi)) { mv = ov; mi = oi; }
            }
            if ((lane & 7) == it) { vy = mv; viy = mi; }
            if (mi == lane)            v0 = -INFINITY;
            else if (mi == lane + 64)  v1 = -INFINITY;
            else if (mi == lane + 128) v2 = -INFINITY;
            else if (mi == lane + 192) v3 = -INFINITY;
        }
    }

    // stage 2: lane = cx*8+cy holds combo score; extract top-8 of 64
    float mycs = vx + vy;                 // combo score (flat index = lane)
    int cidx = vix * NKK + viy;           // expert index
    float s2[8]; int wi2[8];
#pragma unroll
    for (int it = 0; it < 8; ++it) {
        float mv = mycs; int ml = lane;
#pragma unroll
        for (int off = 1; off < 64; off <<= 1) {
            float ov = __shfl_xor(mv, off);
            int ol = __shfl_xor(ml, off);
            if (ov > mv || (ov == mv && ol < ml)) { mv = ov; ml = ol; }
        }
        s2[it] = mv;
        wi2[it] = __shfl(cidx, ml);
        if (lane == ml) mycs = -INFINITY;
    }
    // softmax over the 8 scores (s2[0] is the max)
    float e[8]; float esum = 0.f;
#pragma unroll
    for (int it = 0; it < 8; ++it) { e[it] = expf(s2[it] - s2[0]); esum += e[it]; }
    float inv = 1.f / esum;
    if (lane == 0) {
        int base = (t * HH + h) * TK;
#pragma unroll
        for (int it = 0; it < 8; ++it) { IDX[base + it] = wi2[it]; SMW[base + it] = e[it] * inv; }
    }
}

// ---------------- expert gather + gelu + weighted combine (2-deep pipelined) ----------------
// One block per token, 4 waves; wave w owns experts w*16 .. w*16+15 (heads 2w,2w+1).
// IDX/SMW preloaded to LDS; expert k+1's rows load while expert k computes.
// Arithmetic order per expert is identical to the round-1 kernel.
#define PRELOAD(KIN, KOUT, K)  do {                                          \
    const float* ki_ = key_in  + (size_t)es[eb + (K)] * DD + lane * 4;       \
    const float* ko_ = key_out + (size_t)es[eb + (K)] * DD + lane * 4;       \
    _Pragma("unroll") for (int r = 0; r < 4; ++r) {                          \
        KIN[r]  = *(const float4*)(ki_ + r * 256);                           \
        KOUT[r] = *(const float4*)(ko_ + r * 256); } } while (0)

#define BODY(KIN, KOUT, K) do {                                              \
    float p_ = 0.f;                                                          \
    _Pragma("unroll") for (int r = 0; r < 4; ++r)                            \
        p_ += xin[r].x * KIN[r].x + xin[r].y * KIN[r].y                      \
            + xin[r].z * KIN[r].z + xin[r].w * KIN[r].w;                     \
    _Pragma("unroll") for (int off = 1; off < 64; off <<= 1)                 \
        p_ += __shfl_xor(p_, off);                                           \
    float g_ = 0.5f * p_ * (1.f + erff(p_ * 0.70710678118654752440f));       \
    float go_ = g_ * sw[eb + (K)];                                           \
    _Pragma("unroll") for (int r = 0; r < 4; ++r) {                          \
        acc[r].x += go_ * KOUT[r].x; acc[r].y += go_ * KOUT[r].y;            \
        acc[r].z += go_ * KOUT[r].z; acc[r].w += go_ * KOUT[r].w; } } while (0)

__global__ __launch_bounds__(256) void expert_kernel(
    const float* __restrict__ x, const int* __restrict__ IDX,
    const float* __restrict__ SMW, const float* __restrict__ key_in,
    const float* __restrict__ key_out, float* __restrict__ out)
{
    int t = blockIdx.x;
    int tid = threadIdx.x, lane = tid & 63, w = tid >> 6;
    __shared__ float part[4][DD];
    __shared__ int   es[64];
    __shared__ float sw[64];
    if (tid < 64) { es[tid] = IDX[t * 64 + tid]; sw[tid] = SMW[t * 64 + tid]; }
    float4 xin[4];
#pragma unroll
    for (int r = 0; r < 4; ++r)
        xin[r] = *(const float4*)(x + (size_t)t * DD + r * 256 + lane * 4);
    float4 acc[4];
#pragma unroll
    for (int r = 0; r < 4; ++r) acc[r] = make_float4(0.f, 0.f, 0.f, 0.f);
    __syncthreads();

    int eb = w * 16;
    float4 kinA[4], koutA[4], kinB[4], koutB[4];
    PRELOAD(kinA, koutA, 0);
#pragma unroll
    for (int k = 0; k < 16; k += 2) {
        PRELOAD(kinB, koutB, k + 1);
        BODY(kinA, koutA, k);
        if (k + 2 < 16) PRELOAD(kinA, koutA, k + 2);
        BODY(kinB, koutB, k + 1);
    }

#pragma unroll
    for (int r = 0; r < 4; ++r) *(float4*)&part[w][r * 256 + lane * 4] = acc[r];
    __syncthreads();
    int c = tid * 4;
    float4 s0 = *(const float4*)&part[0][c];
    float4 s1 = *(const float4*)&part[1][c];
    float4 s2 = *(const float4*)&part[2][c];
    float4 s3 = *(const float4*)&part[3][c];
    float4 o;
    o.x = (s0.x + s1.x) + (s2.x + s3.x);
    o.y = (s0.y + s1.y) + (s2.y + s3.y);
    o.z = (s0.z + s1.z) + (s2.z + s3.z);
    o.w = (s0.w + s1.w) + (s2.w + s3.w);
    *(float4*)(out + (size_t)t * DD + c) = o;
}

extern "C" void kernel_launch(void* const* d_in, const int* in_sizes, int n_in,
                              void* d_out, int out_size, void* d_ws, size_t ws_size,
                              hipStream_t stream)
{
    const float* x       = (const float*)d_in[0];
    const float* gamma   = (const float*)d_in[1];
    const float* beta    = (const float*)d_in[2];
    const float* w_q     = (const float*)d_in[3];
    const float* keys    = (const float*)d_in[4];
    const float* key_in  = (const float*)d_in[5];
    const float* key_out = (const float*)d_in[6];
    float* out = (float*)d_out;
    char* ws = (char*)d_ws;

    double* ps  = (double*)(ws + WS_PS);
    double* pq  = (double*)(ws + WS_PQ);
    float*  Aw  = (float*)(ws + WS_A);
    float*  B2w = (float*)(ws + WS_B2);
    float*  XN  = (float*)(ws + WS_XN);
    float*  Q   = (float*)(ws + WS_Q);
    float*  SIMw= (float*)(ws + WS_SIM);
    int*    IDXw= (int*)(ws + WS_IDX);
    float*  SMWw= (float*)(ws + WS_SMW);

    bn_partial<<<dim3(4, 32), 256, 0, stream>>>(x, ps, pq);
    bn_final<<<4, 256, 0, stream>>>(ps, pq, gamma, beta, Aw, B2w);
    xn_kernel<<<2048, 256, 0, stream>>>(x, Aw, B2w, XN);
    // Q = XN @ w_q.T : M=2048 N=2048 K=1024
    gemm_nt<<<dim3(16, 16, 1), 256, 0, stream>>>(XN, w_q, Q, 1024, 1024, 2048, 1024, 0);
    // sim[p][t][h][key] : per (p,h) GEMM, M=2048 N=256 K=128
    gemm_nt<<<dim3(16, 2, 16), 256, 0, stream>>>(Q, keys, SIMw, 2048, 256, 2048, 128, 1);
    topk_kernel<<<4096, 256, 0, stream>>>(SIMw, IDXw, SMWw);
    expert_kernel<<<2048, 256, 0, stream>>>(x, IDXw, SMWw, key_in, key_out, out);
}